// Round 7
// baseline (154.642 us; speedup 1.0000x reference)
//
#include <hip/hip_runtime.h>

#define HW 256
#define CH 64

// 16-lane (DPP row) rotate-and-add; CTRL = 0x120 | n (row_ror:n)
template <int CTRL>
__device__ __forceinline__ float row_rot_add(float v) {
    int r = __builtin_amdgcn_update_dpp(0, __float_as_int(v), CTRL, 0xf, 0xf, false);
    return v + __int_as_float(r);
}

// ---------------- Kernel A: per-(pixel,tap) sample-index computation -------
// Thread u = p*9 + tap. Offset element address = 2u (perfectly linear!).
// Writes packed element-offset (or -1 for zero-ring) to ws[u].
__global__ __launch_bounds__(256) void dcl_index_kernel(
    const float* __restrict__ gt,     // [256,256]
    const float* __restrict__ off,    // [4,256,256,18] == flat [2*2359296]
    int* __restrict__ ws)             // [2359296]
{
    unsigned u = blockIdx.x * 256 + threadIdx.x;      // 0 .. 2359295
    unsigned p = __umulhi(u, 0x38E38E39u) >> 1;       // u / 9
    int tap = u - p * 9;
    int i = (p >> 8) & 255, j = p & 255;
    int ky = tap / 3, kx = tap - ky * 3;

    // linear, fully coalesced offset load
    float2 o2 = *(const float2*)(off + 2ul * u);

    int iy = i + ky - 1, ix = j + kx - 1;
    bool interior = (iy >= 0) & (iy < HW) & (ix >= 0) & (ix < HW);
    int yi = interior ? iy : 0;
    int xi = interior ? ix : 0;
    float yf = (float)yi, xf = (float)xi;

    float p_mask = (yi >= 1 && xi >= 1) ? gt[(yi - 1) * HW + (xi - 1)] : 0.f;

    float yof = fminf(fmaxf(floorf(yf + o2.x), 0.f), 257.f);
    float xof = fminf(fmaxf(floorf(xf + o2.y), 0.f), 257.f);
    int yo = (int)yof, xo = (int)xof;
    float p_mask_off = (yo >= 1 && yo <= HW && xo >= 1 && xo <= HW)
                       ? gt[(yo - 1) * HW + (xo - 1)] : 0.f;
    float diff = (p_mask != p_mask_off) ? 1.f : 0.f;

    float y = fminf(fmaxf(yf + o2.x * diff, 0.f), 255.f);
    float x = fminf(fmaxf(xf + o2.y * diff, 0.f), 255.f);
    int y0 = (int)y, x0 = (int)x;

    bool valid = (y0 >= 1) & (x0 >= 1);
    ws[u] = valid ? ((y0 - 1) * HW + (x0 - 1)) * CH : -1;
}

// ---------------- Kernel B: gather + dot ----------------------------------
// 256 threads = 4 waves; wave = 4 pixels x 16 lanes (lane%16 = channel quad).
// Per pixel: 9 index loads (one 64B line, broadcast across the 16-lane
// group), 9 independent 256B gathers, FMA vs register weights, DPP reduce.
__global__ __launch_bounds__(256) void dcl_gather_kernel(
    const float* __restrict__ inp,    // [4,256,256,64]
    const int*   __restrict__ ws,     // [2359296] packed offsets
    const float* __restrict__ ker,    // [9][64]
    const float* __restrict__ bias,   // [1]
    float* __restrict__ out)          // [4,256,256]
{
    const int tid  = threadIdx.x;
    const int lane = tid & 63;
    const int wave = tid >> 6;
    const int q    = lane >> 4;       // pixel-in-wave 0..3
    const int t    = lane & 15;       // channel quad 0..15

    // XCD swizzle: contiguous 2048-block chunk per XCD
    const int bid = blockIdx.x;
    const int vb  = (bid & 7) * 2048 + (bid >> 3);

    const int p = vb * 16 + wave * 4 + q;
    const int b = p >> 16;
    const float* inb = inp + (long)b * (HW * HW * CH);

    // 9 packed indices for this pixel (group-uniform address -> broadcast)
    int pk[9];
    #pragma unroll
    for (int k = 0; k < 9; ++k) pk[k] = ws[p * 9 + k];

    // weights: 9 taps x this lane's channel quad (L1-resident, independent)
    float4 w[9];
    #pragma unroll
    for (int k = 0; k < 9; ++k)
        w[k] = *(const float4*)(ker + k * CH + t * 4);

    // 9 independent gathers
    float4 v[9];
    #pragma unroll
    for (int k = 0; k < 9; ++k) {
        int eo = pk[k] >= 0 ? pk[k] : 0;
        v[k] = *(const float4*)(inb + eo + t * 4);
    }

    float acc = 0.f;
    #pragma unroll
    for (int k = 0; k < 9; ++k) {
        float d = v[k].x * w[k].x + v[k].y * w[k].y
                + v[k].z * w[k].z + v[k].w * w[k].w;
        acc = fmaf(pk[k] >= 0 ? 1.f : 0.f, d, acc);
    }

    acc = row_rot_add<0x128>(acc);
    acc = row_rot_add<0x124>(acc);
    acc = row_rot_add<0x122>(acc);
    acc = row_rot_add<0x121>(acc);

    if (t == 0) out[p] = acc + bias[0];
}

extern "C" void kernel_launch(void* const* d_in, const int* in_sizes, int n_in,
                              void* d_out, int out_size, void* d_ws, size_t ws_size,
                              hipStream_t stream) {
    const float* inp  = (const float*)d_in[0];
    const float* gt   = (const float*)d_in[1];
    const float* off  = (const float*)d_in[2];
    const float* ker  = (const float*)d_in[3];
    const float* bias = (const float*)d_in[4];
    float* out = (float*)d_out;
    int* ws = (int*)d_ws;             // needs 2359296*4 = 9.4 MB scratch

    // A: 262144*9 = 2359296 threads -> 9216 blocks (linear grid, streaming)
    dcl_index_kernel<<<9216, 256, 0, stream>>>(gt, off, ws);
    // B: 262144 px / 16 per block = 16384 blocks
    dcl_gather_kernel<<<16384, 256, 0, stream>>>(inp, ws, ker, bias, out);
}